// Round 5
// baseline (194.481 us; speedup 1.0000x reference)
//
#include <hip/hip_runtime.h>
#include <math.h>

#define BLOCK 256
#define NBLOCKS 2048
#define EPS 1e-10f
#define LAMBD 0.5f

// Per-float4-pair accumulate: sse += (o-l)^2, sl += l, tp += l*(o>0.5)
#define ACC(o, l)                                                         \
    do {                                                                  \
        float d0 = o.x - l.x, d1 = o.y - l.y;                             \
        float d2 = o.z - l.z, d3 = o.w - l.w;                             \
        sse += d0 * d0 + d1 * d1 + d2 * d2 + d3 * d3;                     \
        sl  += l.x + l.y + l.z + l.w;                                     \
        tp  += (o.x > 0.5f ? l.x : 0.f) + (o.y > 0.5f ? l.y : 0.f)        \
             + (o.z > 0.5f ? l.z : 0.f) + (o.w > 0.5f ? l.w : 0.f);       \
    } while (0)

// Fused grid-stride reduction + last-block finalize.
// Software pipeline (named cur/next register sets): next group's 4 loads are
// issued BEFORE computing the current group, so compute overlaps memory and
// the vmcnt wait lands after the ACC block. Each thread reads 32B per array
// per iteration (2 x dwordx4 at imm offsets 0/+16 from one address).
__global__ __launch_bounds__(BLOCK, 4) void detloss_fused(
    const float4* __restrict__ o4, const float4* __restrict__ l4,
    const float* __restrict__ outp, const float* __restrict__ lab,
    float* __restrict__ part, unsigned int* __restrict__ counter,
    float* __restrict__ out, int n8, long long n, float inv_n) {

    float sse = 0.f, tp = 0.f, sl = 0.f;

    const int stride = gridDim.x * BLOCK;        // in 8-float units
    int i = blockIdx.x * BLOCK + threadIdx.x;

    float4 co0, co1, cl0, cl1;                   // current group (computing)
    bool have = (i < n8);
    if (have) {
        co0 = o4[2 * i]; co1 = o4[2 * i + 1];
        cl0 = l4[2 * i]; cl1 = l4[2 * i + 1];
    }
    while (have) {
        const int ni = i + stride;
        const bool nhave = (ni < n8);
        float4 no0 = co0, no1 = co1, nl0 = cl0, nl1 = cl1;  // init to silence UB
        if (nhave) {                              // issue next loads FIRST
            no0 = o4[2 * ni]; no1 = o4[2 * ni + 1];
            nl0 = l4[2 * ni]; nl1 = l4[2 * ni + 1];
        }
        ACC(co0, cl0);                            // compute current (overlaps)
        ACC(co1, cl1);
        co0 = no0; co1 = no1; cl0 = nl0; cl1 = nl1;
        i = ni; have = nhave;
    }

    // Scalar tail (n not divisible by 8) — thread 0 of block 0.
    if (blockIdx.x == 0 && threadIdx.x == 0) {
        for (long long j = (long long)n8 * 8; j < n; ++j) {
            float o = outp[j], l = lab[j];
            float d = o - l;
            sse += d * d;
            sl  += l;
            tp  += (o > 0.5f ? l : 0.f);
        }
    }

    // Wave-64 reduce -> LDS -> block partials.
    for (int off = 32; off > 0; off >>= 1) {
        sse += __shfl_down(sse, off);
        tp  += __shfl_down(tp,  off);
        sl  += __shfl_down(sl,  off);
    }

    __shared__ float s_sse[BLOCK / 64], s_tp[BLOCK / 64], s_sl[BLOCK / 64];
    __shared__ bool s_last;
    const int lane = threadIdx.x & 63;
    const int wave = threadIdx.x >> 6;
    if (lane == 0) { s_sse[wave] = sse; s_tp[wave] = tp; s_sl[wave] = sl; }
    __syncthreads();

    const int nb = gridDim.x;
    if (threadIdx.x == 0) {
        float bsse = 0.f, btp = 0.f, bsl = 0.f;
        for (int w = 0; w < BLOCK / 64; ++w) {
            bsse += s_sse[w]; btp += s_tp[w]; bsl += s_sl[w];
        }
        part[blockIdx.x]          = bsse;
        part[nb + blockIdx.x]     = btp;
        part[2 * nb + blockIdx.x] = bsl;
        __threadfence();                          // release partials (device scope)
        unsigned old = atomicAdd(counter, 1u);    // device-scope by default
        s_last = (old == (unsigned)nb - 1u);
    }
    __syncthreads();

    if (s_last) {                                 // last arriving block finalizes
        __threadfence();                          // acquire side
        float fs = 0.f, ft = 0.f, fl = 0.f;
        for (int k = threadIdx.x; k < nb; k += BLOCK) {
            fs += part[k];
            ft += part[nb + k];
            fl += part[2 * nb + k];
        }
        for (int off = 32; off > 0; off >>= 1) {
            fs += __shfl_down(fs, off);
            ft += __shfl_down(ft, off);
            fl += __shfl_down(fl, off);
        }
        __syncthreads();                          // protect s_* reuse
        if (lane == 0) { s_sse[wave] = fs; s_tp[wave] = ft; s_sl[wave] = fl; }
        __syncthreads();
        if (threadIdx.x == 0) {
            float S = s_sse[0] + s_sse[1] + s_sse[2] + s_sse[3];
            float T = s_tp[0]  + s_tp[1]  + s_tp[2]  + s_tp[3];
            float L = s_sl[0]  + s_sl[1]  + s_sl[2]  + s_sl[3];
            float fn = L - T;
            float coeff;
            if (T == 0.f && fn == 0.f)      coeff = 1.f;
            else if (T == 0.f)              coeff = 0.f;
            else                            coeff = T / (T + fn);
            out[0] = S * inv_n + LAMBD * (-logf(coeff + EPS));
        }
    }
}

extern "C" void kernel_launch(void* const* d_in, const int* in_sizes, int n_in,
                              void* d_out, int out_size, void* d_ws, size_t ws_size,
                              hipStream_t stream) {
    const float* outp = (const float*)d_in[0];
    const float* lab  = (const float*)d_in[1];
    float* out = (float*)d_out;

    unsigned int* counter = (unsigned int*)d_ws;          // 4 bytes
    float* part = ((float*)d_ws) + 8;                     // 32B-aligned, 3*NBLOCKS floats

    long long n = (long long)in_sizes[0];
    int n8 = (int)(n >> 3);

    int blocks = (n8 + BLOCK - 1) / BLOCK;
    if (blocks > NBLOCKS) blocks = NBLOCKS;
    if (blocks < 1) blocks = 1;

    // Counter must be 0 at kernel start every call (d_ws poisoned once, and we
    // leave the counter at `blocks` after each call) -> 4-byte async memset.
    hipMemsetAsync(counter, 0, sizeof(unsigned int), stream);

    detloss_fused<<<blocks, BLOCK, 0, stream>>>(
        (const float4*)outp, (const float4*)lab, outp, lab,
        part, counter, out, n8, n, 1.0f / (float)n);
}

// Round 7
// 91.816 us; speedup vs baseline: 2.1182x; 2.1182x over previous
//
#include <hip/hip_runtime.h>
#include <math.h>

#define BLOCK 256
#define NBLOCKS 2048
#define UNROLL 4
#define EPS 1e-10f
#define LAMBD 0.5f

// Native clang vector type — __builtin_nontemporal_load requires it
// (HIP_vector_type float4 is a struct and is rejected).
typedef float vf4 __attribute__((ext_vector_type(4)));

// Per-element accumulate: sse += (o-l)^2, sl += l, tp += l*(o>0.5)
#define ACC(o, l)                                                         \
    do {                                                                  \
        float d0 = o.x - l.x, d1 = o.y - l.y;                             \
        float d2 = o.z - l.z, d3 = o.w - l.w;                             \
        sse += d0 * d0 + d1 * d1 + d2 * d2 + d3 * d3;                     \
        sl  += l.x + l.y + l.z + l.w;                                     \
        tp  += (o.x > 0.5f ? l.x : 0.f) + (o.y > 0.5f ? l.y : 0.f)        \
             + (o.z > 0.5f ? l.z : 0.f) + (o.w > 0.5f ? l.w : 0.f);       \
    } while (0)

// Grid-stride reduction, 4x unrolled (R4 structure — best so far), with
// NON-TEMPORAL loads: the 512MB stream is touched once per call, so mark it
// evict-first (global_load_dwordx4 ... nt) to take the streaming path instead
// of thrashing L2/L3. sched_barrier pins the 8-load cluster before compute.
__global__ __launch_bounds__(BLOCK, 4) void detloss_reduce(
    const vf4* __restrict__ o4, const vf4* __restrict__ l4,
    float* __restrict__ part, int n4, long long n,
    const float* __restrict__ outp, const float* __restrict__ lab) {

    float sse = 0.f, tp = 0.f, sl = 0.f;

    const int stride = gridDim.x * BLOCK;          // float4 units
    const int chunk  = stride * UNROLL;
    const int n_main = (n4 / chunk) * chunk;

    int i = blockIdx.x * BLOCK + threadIdx.x;

    for (; i < n_main; i += chunk) {
        // 8 independent non-temporal 16B loads, pinned before any compute.
        vf4 o0 = __builtin_nontemporal_load(&o4[i             ]);
        vf4 l0 = __builtin_nontemporal_load(&l4[i             ]);
        vf4 o1 = __builtin_nontemporal_load(&o4[i +     stride]);
        vf4 l1 = __builtin_nontemporal_load(&l4[i +     stride]);
        vf4 o2 = __builtin_nontemporal_load(&o4[i + 2 * stride]);
        vf4 l2 = __builtin_nontemporal_load(&l4[i + 2 * stride]);
        vf4 o3 = __builtin_nontemporal_load(&o4[i + 3 * stride]);
        vf4 l3 = __builtin_nontemporal_load(&l4[i + 3 * stride]);
        __builtin_amdgcn_sched_barrier(0);   // loads above, compute below
        ACC(o0, l0); ACC(o1, l1); ACC(o2, l2); ACC(o3, l3);
    }

    // Remainder float4s (grid-stride).
    for (; i < n4; i += stride) {
        vf4 o = __builtin_nontemporal_load(&o4[i]);
        vf4 l = __builtin_nontemporal_load(&l4[i]);
        ACC(o, l);
    }

    // Scalar tail (n not divisible by 4) — thread 0 of block 0.
    if (blockIdx.x == 0 && threadIdx.x == 0) {
        for (long long j = (long long)n4 << 2; j < n; ++j) {
            float o = outp[j], l = lab[j];
            float d = o - l;
            sse += d * d;
            sl  += l;
            tp  += (o > 0.5f ? l : 0.f);
        }
    }

    // Wave-64 reduce.
    for (int off = 32; off > 0; off >>= 1) {
        sse += __shfl_down(sse, off);
        tp  += __shfl_down(tp,  off);
        sl  += __shfl_down(sl,  off);
    }

    __shared__ float s_sse[BLOCK / 64], s_tp[BLOCK / 64], s_sl[BLOCK / 64];
    const int lane = threadIdx.x & 63;
    const int wave = threadIdx.x >> 6;
    if (lane == 0) { s_sse[wave] = sse; s_tp[wave] = tp; s_sl[wave] = sl; }
    __syncthreads();

    if (threadIdx.x == 0) {
        float bsse = 0.f, btp = 0.f, bsl = 0.f;
        for (int w = 0; w < BLOCK / 64; ++w) {
            bsse += s_sse[w]; btp += s_tp[w]; bsl += s_sl[w];
        }
        const int nb = gridDim.x;
        part[blockIdx.x]          = bsse;
        part[nb + blockIdx.x]     = btp;
        part[2 * nb + blockIdx.x] = bsl;
    }
}

// Final: one 256-thread block reduces nblk x 3 partials + epilogue.
__global__ __launch_bounds__(256) void detloss_final(
    const float* __restrict__ part, int nblk,
    float* __restrict__ out, float inv_n) {

    float sse = 0.f, tp = 0.f, sl = 0.f;
    for (int i = threadIdx.x; i < nblk; i += 256) {
        sse += part[i];
        tp  += part[nblk + i];
        sl  += part[2 * nblk + i];
    }
    for (int off = 32; off > 0; off >>= 1) {
        sse += __shfl_down(sse, off);
        tp  += __shfl_down(tp,  off);
        sl  += __shfl_down(sl,  off);
    }
    __shared__ float s[3][4];
    const int lane = threadIdx.x & 63;
    const int wave = threadIdx.x >> 6;
    if (lane == 0) { s[0][wave] = sse; s[1][wave] = tp; s[2][wave] = sl; }
    __syncthreads();

    if (threadIdx.x == 0) {
        sse = s[0][0] + s[0][1] + s[0][2] + s[0][3];
        tp  = s[1][0] + s[1][1] + s[1][2] + s[1][3];
        sl  = s[2][0] + s[2][1] + s[2][2] + s[2][3];
        float fn = sl - tp;
        float coeff;
        if (tp == 0.f && fn == 0.f)      coeff = 1.f;
        else if (tp == 0.f)              coeff = 0.f;
        else                             coeff = tp / (tp + fn);
        float cost = -logf(coeff + EPS);
        out[0] = sse * inv_n + LAMBD * cost;
    }
}

extern "C" void kernel_launch(void* const* d_in, const int* in_sizes, int n_in,
                              void* d_out, int out_size, void* d_ws, size_t ws_size,
                              hipStream_t stream) {
    const float* outp = (const float*)d_in[0];
    const float* lab  = (const float*)d_in[1];
    float* out  = (float*)d_out;
    float* part = (float*)d_ws;   // 3 * NBLOCKS floats = 24 KB

    long long n = (long long)in_sizes[0];
    int n4 = (int)(n >> 2);

    int blocks = (n4 + BLOCK - 1) / BLOCK;
    if (blocks > NBLOCKS) blocks = NBLOCKS;
    if (blocks < 1) blocks = 1;

    detloss_reduce<<<blocks, BLOCK, 0, stream>>>(
        (const vf4*)outp, (const vf4*)lab, part, n4, n, outp, lab);
    detloss_final<<<1, 256, 0, stream>>>(part, blocks, out, 1.0f / (float)n);
}

// Round 8
// 90.421 us; speedup vs baseline: 2.1508x; 1.0154x over previous
//
#include <hip/hip_runtime.h>
#include <math.h>

#define BLOCK 256
#define NBLOCKS 2048
#define UNROLL 4
#define EPS 1e-10f
#define LAMBD 0.5f

// Native clang vector type — __builtin_nontemporal_load requires it
// (HIP_vector_type float4 is a struct and is rejected).
typedef float vf4 __attribute__((ext_vector_type(4)));

// Per-element accumulate: sse += (o-l)^2, sl += l, tp += l*(o>0.5)
#define ACC(o, l)                                                         \
    do {                                                                  \
        float d0 = o.x - l.x, d1 = o.y - l.y;                             \
        float d2 = o.z - l.z, d3 = o.w - l.w;                             \
        sse += d0 * d0 + d1 * d1 + d2 * d2 + d3 * d3;                     \
        sl  += l.x + l.y + l.z + l.w;                                     \
        tp  += (o.x > 0.5f ? l.x : 0.f) + (o.y > 0.5f ? l.y : 0.f)        \
             + (o.z > 0.5f ? l.z : 0.f) + (o.w > 0.5f ? l.w : 0.f);       \
    } while (0)

// Grid-stride reduction, 4x unrolled. HYBRID cache policy:
//   outputs: CACHED loads  -> 256MB = one Infinity-Cache's worth; bias it to
//            stay L3-resident across graph replays (R4 evidence: FETCH_SIZE
//            was 250MB of 512MB -> L3 retains half the working set).
//   labels:  NON-TEMPORAL  -> evict-first, streams from HBM without
//            displacing the outputs lines.
// HBM then carries ~256MB/call while L3 serves the rest concurrently.
__global__ __launch_bounds__(BLOCK, 4) void detloss_reduce(
    const vf4* __restrict__ o4, const vf4* __restrict__ l4,
    float* __restrict__ part, int n4, long long n,
    const float* __restrict__ outp, const float* __restrict__ lab) {

    float sse = 0.f, tp = 0.f, sl = 0.f;

    const int stride = gridDim.x * BLOCK;          // float4 units
    const int chunk  = stride * UNROLL;
    const int n_main = (n4 / chunk) * chunk;

    int i = blockIdx.x * BLOCK + threadIdx.x;

    for (; i < n_main; i += chunk) {
        // 8 independent 16B loads, pinned before any compute.
        vf4 o0 = o4[i             ];
        vf4 l0 = __builtin_nontemporal_load(&l4[i             ]);
        vf4 o1 = o4[i +     stride];
        vf4 l1 = __builtin_nontemporal_load(&l4[i +     stride]);
        vf4 o2 = o4[i + 2 * stride];
        vf4 l2 = __builtin_nontemporal_load(&l4[i + 2 * stride]);
        vf4 o3 = o4[i + 3 * stride];
        vf4 l3 = __builtin_nontemporal_load(&l4[i + 3 * stride]);
        __builtin_amdgcn_sched_barrier(0);   // loads above, compute below
        ACC(o0, l0); ACC(o1, l1); ACC(o2, l2); ACC(o3, l3);
    }

    // Remainder float4s (grid-stride).
    for (; i < n4; i += stride) {
        vf4 o = o4[i];
        vf4 l = __builtin_nontemporal_load(&l4[i]);
        ACC(o, l);
    }

    // Scalar tail (n not divisible by 4) — thread 0 of block 0.
    if (blockIdx.x == 0 && threadIdx.x == 0) {
        for (long long j = (long long)n4 << 2; j < n; ++j) {
            float o = outp[j], l = lab[j];
            float d = o - l;
            sse += d * d;
            sl  += l;
            tp  += (o > 0.5f ? l : 0.f);
        }
    }

    // Wave-64 reduce.
    for (int off = 32; off > 0; off >>= 1) {
        sse += __shfl_down(sse, off);
        tp  += __shfl_down(tp,  off);
        sl  += __shfl_down(sl,  off);
    }

    __shared__ float s_sse[BLOCK / 64], s_tp[BLOCK / 64], s_sl[BLOCK / 64];
    const int lane = threadIdx.x & 63;
    const int wave = threadIdx.x >> 6;
    if (lane == 0) { s_sse[wave] = sse; s_tp[wave] = tp; s_sl[wave] = sl; }
    __syncthreads();

    if (threadIdx.x == 0) {
        float bsse = 0.f, btp = 0.f, bsl = 0.f;
        for (int w = 0; w < BLOCK / 64; ++w) {
            bsse += s_sse[w]; btp += s_tp[w]; bsl += s_sl[w];
        }
        const int nb = gridDim.x;
        part[blockIdx.x]          = bsse;
        part[nb + blockIdx.x]     = btp;
        part[2 * nb + blockIdx.x] = bsl;
    }
}

// Final: one 256-thread block reduces nblk x 3 partials + epilogue.
__global__ __launch_bounds__(256) void detloss_final(
    const float* __restrict__ part, int nblk,
    float* __restrict__ out, float inv_n) {

    float sse = 0.f, tp = 0.f, sl = 0.f;
    for (int i = threadIdx.x; i < nblk; i += 256) {
        sse += part[i];
        tp  += part[nblk + i];
        sl  += part[2 * nblk + i];
    }
    for (int off = 32; off > 0; off >>= 1) {
        sse += __shfl_down(sse, off);
        tp  += __shfl_down(tp,  off);
        sl  += __shfl_down(sl,  off);
    }
    __shared__ float s[3][4];
    const int lane = threadIdx.x & 63;
    const int wave = threadIdx.x >> 6;
    if (lane == 0) { s[0][wave] = sse; s[1][wave] = tp; s[2][wave] = sl; }
    __syncthreads();

    if (threadIdx.x == 0) {
        sse = s[0][0] + s[0][1] + s[0][2] + s[0][3];
        tp  = s[1][0] + s[1][1] + s[1][2] + s[1][3];
        sl  = s[2][0] + s[2][1] + s[2][2] + s[2][3];
        float fn = sl - tp;
        float coeff;
        if (tp == 0.f && fn == 0.f)      coeff = 1.f;
        else if (tp == 0.f)              coeff = 0.f;
        else                             coeff = tp / (tp + fn);
        float cost = -logf(coeff + EPS);
        out[0] = sse * inv_n + LAMBD * cost;
    }
}

extern "C" void kernel_launch(void* const* d_in, const int* in_sizes, int n_in,
                              void* d_out, int out_size, void* d_ws, size_t ws_size,
                              hipStream_t stream) {
    const float* outp = (const float*)d_in[0];
    const float* lab  = (const float*)d_in[1];
    float* out  = (float*)d_out;
    float* part = (float*)d_ws;   // 3 * NBLOCKS floats = 24 KB

    long long n = (long long)in_sizes[0];
    int n4 = (int)(n >> 2);

    int blocks = (n4 + BLOCK - 1) / BLOCK;
    if (blocks > NBLOCKS) blocks = NBLOCKS;
    if (blocks < 1) blocks = 1;

    detloss_reduce<<<blocks, BLOCK, 0, stream>>>(
        (const vf4*)outp, (const vf4*)lab, part, n4, n, outp, lab);
    detloss_final<<<1, 256, 0, stream>>>(part, blocks, out, 1.0f / (float)n);
}